// Round 6
// baseline (149.388 us; speedup 1.0000x reference)
//
#include <hip/hip_runtime.h>
#include <cmath>

// CapsuleLayer routing, B=64, Ni=2048, Di=16, No=32, Do=16 (fp32 in/out).
// R6: latency-first redesign. W never touches LDS: each wave global-loads its
// o-slices directly in MFMA A-fragment lane order (proven R3), converts
// split-bf16 in-reg, prefetched one full n-iteration ahead. x is staged as
// split-bf16 B-frags ONCE for all 8 n. Loop has only 2 tiny barriers/n for
// the hsum -> softmax -> c2 exchange. Grid 1024 = 256 ng x 4 b-quarters;
// same-ng blocks share an XCD (bid%8) for L2 reuse; L3 dedups W re-reads.

#define NI 2048

typedef short bf16x8 __attribute__((ext_vector_type(8)));
typedef float f32x4 __attribute__((ext_vector_type(4)));

static __device__ __forceinline__ unsigned short f2bf(float f) {
  unsigned u = __float_as_uint(f);
  u += 0x7FFFu + ((u >> 16) & 1u);
  return (unsigned short)(u >> 16);
}
static __device__ __forceinline__ float bf2f(unsigned short h) {
  return __uint_as_float(((unsigned)h) << 16);
}

// LDS dword map
#define XB0_OFF 0      // 8 n * 256 dw : x_hi B-frags (dup across k-halves)
#define XB1_OFF 2048   // x_lo B-frags
#define HS_OFF  4096   // 32*17 : hsum[o][b]
#define C2_OFF  4640   // 32*17 : c2[o][b]
#define LDS_DW  5184   // 20.7 KB

__global__ __launch_bounds__(512, 4) void caps_fused_kernel(
    const float* __restrict__ x, const float* __restrict__ W,
    float* __restrict__ partial)
{
  const int bid = blockIdx.x;
  const int ng = bid & 255, bq = bid >> 8;   // same-ng blocks: same bid%8 -> same XCD
  const int t = threadIdx.x;
  const int wv = t >> 6, l = t & 63;
  const int q = l >> 4, dq = l & 15, qh = q & 1;
  const int n0 = ng * 8;

  __shared__ __align__(16) float lds[LDS_DW];

  // ---- one-time: stage x as split-bf16 B-frags for all 8 n ----
  // B-frag lane l needs x[b = bq*16 + (l&15)][i = ((l>>4)&1)*8 + j];
  // lanes l and l+32 duplicate (both K-halves of the dup'd B operand).
  if (t < 256) {
    const int n = t & 7, lh = t >> 3;            // lh 0..31
    const int b = bq * 16 + (lh & 15);
    const int ib = (lh >> 4) * 8;
    const float* xp = x + (size_t)b * (NI * 16) + (size_t)(n0 + n) * 16 + ib;
    float4 va = *(const float4*)xp;
    float4 vb = *(const float4*)(xp + 4);
    float v[8] = {va.x, va.y, va.z, va.w, vb.x, vb.y, vb.z, vb.w};
    bf16x8 hi8, lo8;
    #pragma unroll
    for (int j = 0; j < 8; ++j) {
      unsigned short h = f2bf(v[j]);
      hi8[j] = (short)h;
      lo8[j] = (short)f2bf(v[j] - bf2f(h));
    }
    *(bf16x8*)&lds[XB0_OFF + n * 256 + lh * 4]        = hi8;
    *(bf16x8*)&lds[XB0_OFF + n * 256 + (lh + 32) * 4] = hi8;
    *(bf16x8*)&lds[XB1_OFF + n * 256 + lh * 4]        = lo8;
    *(bf16x8*)&lds[XB1_OFF + n * 256 + (lh + 32) * 4] = lo8;
  }

  // ---- preload W for n0: lane (q,dq) of wave wv, o = wv*4+oo ----
  // A-frag: lane holds A[m=dq][k=q*8+j]; k<16 = W_hi[i=k], k>=16 = W_lo.
  // q pairs (0,2) load i0-7, (1,3) load i8-15 (L1 serves the dup).
  float wbuf[4][8];
  #pragma unroll
  for (int oo = 0; oo < 4; ++oo) {
    const float* wp = W + (size_t)n0 * 8192 + (wv * 4 + oo) * 256 + dq * 16 + qh * 8;
    float4 a = *(const float4*)wp;
    float4 b4 = *(const float4*)(wp + 4);
    wbuf[oo][0] = a.x;  wbuf[oo][1] = a.y;  wbuf[oo][2] = a.z;  wbuf[oo][3] = a.w;
    wbuf[oo][4] = b4.x; wbuf[oo][5] = b4.y; wbuf[oo][6] = b4.z; wbuf[oo][7] = b4.w;
  }
  __syncthreads();

  float sacc[4][4];
  #pragma unroll
  for (int oo = 0; oo < 4; ++oo)
    { sacc[oo][0]=0.f; sacc[oo][1]=0.f; sacc[oo][2]=0.f; sacc[oo][3]=0.f; }

  #pragma unroll 1
  for (int nn = 0; nn < 8; ++nn) {
    // ---- convert wbuf -> A-frags (q<2: hi, q>=2: lo), then prefetch nn+1 ----
    bf16x8 Af[4];
    #pragma unroll
    for (int oo = 0; oo < 4; ++oo) {
      bf16x8 f;
      #pragma unroll
      for (int j = 0; j < 8; ++j) {
        float w = wbuf[oo][j];
        unsigned short h = f2bf(w);
        unsigned short g = f2bf(w - bf2f(h));
        f[j] = (short)(q < 2 ? h : g);
      }
      Af[oo] = f;
    }
    if (nn < 7) {
      #pragma unroll
      for (int oo = 0; oo < 4; ++oo) {
        const float* wp = W + (size_t)(n0 + nn + 1) * 8192
                        + (wv * 4 + oo) * 256 + dq * 16 + qh * 8;
        float4 a = *(const float4*)wp;
        float4 b4 = *(const float4*)(wp + 4);
        wbuf[oo][0] = a.x;  wbuf[oo][1] = a.y;  wbuf[oo][2] = a.z;  wbuf[oo][3] = a.w;
        wbuf[oo][4] = b4.x; wbuf[oo][5] = b4.y; wbuf[oo][6] = b4.z; wbuf[oo][7] = b4.w;
      }
    }

    // ---- MFMA uhat + hsum (sum over d) ----
    f32x4 D[4];
    const bf16x8 B0 = *(const bf16x8*)&lds[XB0_OFF + nn * 256 + l * 4];
    const bf16x8 B1 = *(const bf16x8*)&lds[XB1_OFF + nn * 256 + l * 4];
    #pragma unroll
    for (int oo = 0; oo < 4; ++oo) {
      f32x4 d0 = {0.f, 0.f, 0.f, 0.f};
      d0 = __builtin_amdgcn_mfma_f32_16x16x32_bf16(Af[oo], B0, d0, 0, 0, 0);
      d0 = __builtin_amdgcn_mfma_f32_16x16x32_bf16(Af[oo], B1, d0, 0, 0, 0);
      D[oo] = d0;
      float hs = d0[0] + d0[1] + d0[2] + d0[3];   // rows q*4..q*4+3
      hs += __shfl_xor(hs, 16);
      hs += __shfl_xor(hs, 32);                    // full 16-d sum
      if (q == 0) lds[HS_OFF + (wv * 4 + oo) * 17 + dq] = hs;
    }
    __syncthreads();

    // ---- routing chain (proven): 128 threads = 16 b x 8 oq ----
    if (t < 128) {
      const int bl = t >> 3, oq = t & 7;
      float h[4], b1[4], e[4];
      #pragma unroll
      for (int jj = 0; jj < 4; ++jj) h[jj] = lds[HS_OFF + (oq + (jj << 3)) * 17 + bl];
      float mx = -1e30f;
      #pragma unroll
      for (int jj = 0; jj < 4; ++jj) { b1[jj] = h[jj] * 0.03125f; mx = fmaxf(mx, b1[jj]); }
      mx = fmaxf(mx, __shfl_xor(mx, 1)); mx = fmaxf(mx, __shfl_xor(mx, 2)); mx = fmaxf(mx, __shfl_xor(mx, 4));
      float S = 0.f;
      #pragma unroll
      for (int jj = 0; jj < 4; ++jj) { e[jj] = __expf(b1[jj] - mx); S += e[jj]; }
      S += __shfl_xor(S, 1); S += __shfl_xor(S, 2); S += __shfl_xor(S, 4);
      float inv = 1.0f / S;
      float b2[4]; float mx2 = -1e30f;
      #pragma unroll
      for (int jj = 0; jj < 4; ++jj) { b2[jj] = b1[jj] + e[jj] * inv * h[jj]; mx2 = fmaxf(mx2, b2[jj]); }
      mx2 = fmaxf(mx2, __shfl_xor(mx2, 1)); mx2 = fmaxf(mx2, __shfl_xor(mx2, 2)); mx2 = fmaxf(mx2, __shfl_xor(mx2, 4));
      float S2 = 0.f;
      #pragma unroll
      for (int jj = 0; jj < 4; ++jj) { e[jj] = __expf(b2[jj] - mx2); S2 += e[jj]; }
      S2 += __shfl_xor(S2, 1); S2 += __shfl_xor(S2, 2); S2 += __shfl_xor(S2, 4);
      float inv2 = 1.0f / S2;
      #pragma unroll
      for (int jj = 0; jj < 4; ++jj) lds[C2_OFF + (oq + (jj << 3)) * 17 + bl] = e[jj] * inv2;
    }
    __syncthreads();

    // ---- c2-weighted accumulate (C2 read is a broadcast across q) ----
    #pragma unroll
    for (int oo = 0; oo < 4; ++oo) {
      float c = lds[C2_OFF + (wv * 4 + oo) * 17 + dq];
      sacc[oo][0] += c * D[oo][0]; sacc[oo][1] += c * D[oo][1];
      sacc[oo][2] += c * D[oo][2]; sacc[oo][3] += c * D[oo][3];
    }
  }

  // ---- epilogue: block-contiguous 32 KB slab: partial[bid][b_local][o][d] ----
  #pragma unroll
  for (int oo = 0; oo < 4; ++oo) {
    *(float4*)(partial + (size_t)bid * 8192 + (size_t)dq * 512
               + (wv * 4 + oo) * 16 + q * 4)
        = make_float4(sacc[oo][0], sacc[oo][1], sacc[oo][2], sacc[oo][3]);
  }
}

// ---------------- reduce 256 ng-partials + squash (float4) ----------------
__global__ __launch_bounds__(256) void caps_reduce_kernel(
    const float* __restrict__ partial, float* __restrict__ out)
{
  const int t = threadIdx.x;
  const int w4 = t >> 6, ln = t & 63;
  const int pair = blockIdx.x * 4 + w4;     // (b,o), 2048 total
  const int b = pair >> 5, o = pair & 31;
  const int bq = b >> 4, bl = b & 15;
  const int cg = ln >> 2, dv = ln & 3;
  const float* p = partial + (size_t)bq * (256 * 8192) + bl * 512 + o * 16 + dv * 4;
  float s0 = 0.f, s1 = 0.f, s2a = 0.f, s3 = 0.f;
  #pragma unroll 4
  for (int gg = cg; gg < 256; gg += 16) {
    float4 v = *(const float4*)(p + (size_t)gg * 8192);
    s0 += v.x; s1 += v.y; s2a += v.z; s3 += v.w;
  }
  #pragma unroll
  for (int mk = 4; mk <= 32; mk <<= 1) {
    s0 += __shfl_xor(s0, mk); s1 += __shfl_xor(s1, mk);
    s2a += __shfl_xor(s2a, mk); s3 += __shfl_xor(s3, mk);
  }
  float s2 = s0 * s0 + s1 * s1 + s2a * s2a + s3 * s3;
  s2 += __shfl_xor(s2, 1); s2 += __shfl_xor(s2, 2);    // over dv
  float scale = s2 / (1.0f + s2) / sqrtf(s2 + 1e-7f);
  if (ln < 4)
    *(float4*)(out + (size_t)b * 512 + o * 16 + ln * 4)
        = make_float4(scale * s0, scale * s1, scale * s2a, scale * s3);
}

extern "C" void kernel_launch(void* const* d_in, const int* in_sizes, int n_in,
                              void* d_out, int out_size, void* d_ws, size_t ws_size,
                              hipStream_t stream) {
  const float* x = (const float*)d_in[0];   // [64,2048,16]
  const float* W = (const float*)d_in[1];   // [1,2048,32,16,16]
  if (in_sizes[0] != 64 * 2048 * 16) { const float* tmp = x; x = W; W = tmp; }
  float* out = (float*)d_out;               // [64,32,16]

  float* partial = (float*)d_ws;            // 1024 blocks * 8192 f32 = 32 MB

  caps_fused_kernel<<<1024, 512, 0, stream>>>(x, W, partial);
  caps_reduce_kernel<<<512, 256, 0, stream>>>(partial, out);
}